// Round 1
// baseline (3064.823 us; speedup 1.0000x reference)
//
#include <hip/hip_runtime.h>

// ---------------- problem constants ----------------
#define NS   4096      // sequence length
#define NBAT 2         // batch
#define NH   4         // heads
#define DKH  256       // head qk dim
#define DVH  512       // head v dim
#define DM   1024      // d_model
#define VD   2048      // value dim
#define CH   64        // chunk
#define NCH  64        // num chunks

typedef unsigned short u16;
typedef unsigned int   u32;

__device__ __forceinline__ float bf2f(u16 a) {
  return __uint_as_float(((u32)a) << 16);
}
__device__ __forceinline__ u16 f2bf(float f) {
  u32 u = __float_as_uint(f);
  u32 r = (u + 0x7fffu + ((u >> 16) & 1u)) >> 16;   // RNE
  return (u16)r;
}
__device__ __forceinline__ void unpack2(u32 v, float& lo, float& hi) {
  lo = __uint_as_float(v << 16);
  hi = __uint_as_float(v & 0xffff0000u);
}
__device__ __forceinline__ void unpack8(uint4 v, float* f) {
  unpack2(v.x, f[0], f[1]); unpack2(v.y, f[2], f[3]);
  unpack2(v.z, f[4], f[5]); unpack2(v.w, f[6], f[7]);
}

// ---------------- generic tiled GEMM: C = A @ B ----------------
// A: MxK row-major (f32 or bf16), B: KxN row-major f32, C: MxN (bf16 or f32)
// 64x64 tile, 256 threads, 4x4 microtile, K-tile 16. As stored transposed.
template<bool ABF, bool OBF>
__global__ __launch_bounds__(256) void gemm64(const void* __restrict__ Ap,
                                              const float* __restrict__ Bp,
                                              void* __restrict__ Cp,
                                              int M, int N, int K) {
  __shared__ float As[16][68];   // [kk][m], padded
  __shared__ float Bs[16][68];   // [kk][n], padded
  const int tid = threadIdx.x;
  const int tx = tid & 15, ty = tid >> 4;
  const int row0 = blockIdx.y << 6, col0 = blockIdx.x << 6;
  const int ar = tid >> 2, ak = (tid & 3) << 2;   // A stage: row ar, kk ak..ak+3
  const int bk = tid >> 4, bc = (tid & 15) << 2;  // B stage: kk bk, col bc..bc+3
  float acc[4][4] = {};
  for (int k0 = 0; k0 < K; k0 += 16) {
    float a0, a1, a2, a3;
    if constexpr (ABF) {
      const u16* A16 = (const u16*)Ap;
      ushort4 a = *(const ushort4*)(A16 + (size_t)(row0 + ar) * K + k0 + ak);
      a0 = bf2f(a.x); a1 = bf2f(a.y); a2 = bf2f(a.z); a3 = bf2f(a.w);
    } else {
      const float* Af = (const float*)Ap;
      float4 a = *(const float4*)(Af + (size_t)(row0 + ar) * K + k0 + ak);
      a0 = a.x; a1 = a.y; a2 = a.z; a3 = a.w;
    }
    As[ak + 0][ar] = a0; As[ak + 1][ar] = a1;
    As[ak + 2][ar] = a2; As[ak + 3][ar] = a3;
    float4 bv = *(const float4*)(Bp + (size_t)(k0 + bk) * N + col0 + bc);
    *(float4*)&Bs[bk][bc] = bv;
    __syncthreads();
#pragma unroll
    for (int kk = 0; kk < 16; kk++) {
      float4 av  = *(const float4*)&As[kk][ty << 2];
      float4 bv2 = *(const float4*)&Bs[kk][tx << 2];
      float aa[4] = {av.x, av.y, av.z, av.w};
      float bb[4] = {bv2.x, bv2.y, bv2.z, bv2.w};
#pragma unroll
      for (int i2 = 0; i2 < 4; i2++)
#pragma unroll
        for (int j2 = 0; j2 < 4; j2++)
          acc[i2][j2] += aa[i2] * bb[j2];
    }
    __syncthreads();
  }
#pragma unroll
  for (int i2 = 0; i2 < 4; i2++) {
    const size_t row = (size_t)row0 + (ty << 2) + i2;
    if constexpr (OBF) {
      u16* C16 = (u16*)Cp;
      ushort4 o;
      o.x = f2bf(acc[i2][0]); o.y = f2bf(acc[i2][1]);
      o.z = f2bf(acc[i2][2]); o.w = f2bf(acc[i2][3]);
      *(ushort4*)(C16 + row * N + col0 + (tx << 2)) = o;
    } else {
      float* Cf = (float*)Cp;
      float4 o = {acc[i2][0], acc[i2][1], acc[i2][2], acc[i2][3]};
      *(float4*)(Cf + row * N + col0 + (tx << 2)) = o;
    }
  }
}

// ---------------- RoPE (in-place on bf16 Q,K) + q scale ----------------
// thread t -> (bn, h, j) with j in 0..127 (rotate-half pairs j, j+128)
__global__ __launch_bounds__(256) void rope_kernel(u16* __restrict__ Q, u16* __restrict__ K) {
  size_t t = (size_t)blockIdx.x * 256 + threadIdx.x;   // B*N*NH*128 total
  int j = (int)(t & 127);
  int h = (int)((t >> 7) & 3);
  size_t bn = t >> 9;
  int n = (int)(bn & (NS - 1));
  // inv_freq = 10000^(-j/128) = 2^(-j*log2(10000)/128)
  float ang = (float)n * exp2f(-(float)j * (13.2877123795494f / 128.0f));
  float s, c;
  sincosf(ang, &s, &c);
  size_t base = bn * DM + (size_t)h * DKH + j;
  const float sc = 0.0625f;   // HEAD_QK^-0.5
  float q1 = bf2f(Q[base]), q2 = bf2f(Q[base + 128]);
  Q[base]       = f2bf((q1 * c - q2 * s) * sc);
  Q[base + 128] = f2bf((q2 * c + q1 * s) * sc);
  float k1 = bf2f(K[base]), k2 = bf2f(K[base + 128]);
  K[base]       = f2bf(k1 * c - k2 * s);
  K[base + 128] = f2bf(k2 * c + k1 * s);
}

// ---------------- attention scores with decay, per (b,h,chunk) ----------------
// writes attnT[j][i] = gamma^(i-j) * (q_i . k_j)  for i>=j else 0
__global__ __launch_bounds__(256) void attn_kernel(const u16* __restrict__ Q,
                                                   const u16* __restrict__ Kb,
                                                   float* __restrict__ AttnT) {
  __shared__ u16 sK[64][264];   // row stride 264 bf16 = 528B (16B aligned)
  const int wg = blockIdx.x;          // (b*4+h)*64 + tc
  const int tc = wg & 63, h = (wg >> 6) & 3, b = wg >> 8;
  const int n0 = tc << 6;
  const int tid = threadIdx.x;
  {
    const int r = tid >> 2, c0 = (tid & 3) << 6;
    const u16* src = Kb + (size_t)(b * NS + n0 + r) * DM + h * DKH + c0;
#pragma unroll
    for (int u = 0; u < 8; u++)
      *(uint4*)&sK[r][c0 + u * 8] = *(const uint4*)(src + u * 8);
  }
  __syncthreads();
  const int i = tid >> 2, jg = tid & 3;
  const u16* qrow = Q + (size_t)(b * NS + n0 + i) * DM + h * DKH;
  float acc[16] = {};
  for (int d0 = 0; d0 < 256; d0 += 8) {
    uint4 qv = *(const uint4*)(qrow + d0);
    float qf[8]; unpack8(qv, qf);
#pragma unroll
    for (int jj = 0; jj < 16; jj++) {
      uint4 kv = *(const uint4*)&sK[jg * 16 + jj][d0];
      float kf[8]; unpack8(kv, kf);
#pragma unroll
      for (int u = 0; u < 8; u++) acc[jj] += qf[u] * kf[u];
    }
  }
  const float gamma = 1.0f - exp2f(-5.0f - (float)h);
  const float l2g = log2f(gamma);
  float* dst = AttnT + ((size_t)wg << 12) + i;
#pragma unroll
  for (int jj = 0; jj < 16; jj++) {
    int j = jg * 16 + jj;
    int rel = i - j;
    float v = (rel >= 0) ? acc[jj] * exp2f((float)rel * l2g) : 0.0f;
    dst[(size_t)j << 6] = v;
  }
}

// ---------------- retention scan ----------------
// 512 wgs: (b,h,eb) eb = 8-col slice of the 512-wide value dim.
// S (256x8 f32) persists in LDS across the 64-chunk serial loop.
__global__ __launch_bounds__(256) void scan_kernel(const u16* __restrict__ Q,
                                                   const u16* __restrict__ Kb,
                                                   const u16* __restrict__ V,
                                                   const float* __restrict__ AttnT,
                                                   u16* __restrict__ O) {
  __shared__ u16 sQ[64][258];     // odd dword stride -> conflict-free [i][d] reads
  __shared__ float sS[256][10];   // [d][e], padded for float2 e-pair reads
  __shared__ u16 sV[64][8];
  __shared__ float sCK[64];
  const int wg = blockIdx.x;
  const int eb = wg & 63, h = (wg >> 6) & 3, b = wg >> 8;
  const int tid = threadIdx.x;
  const float gamma = 1.0f - exp2f(-5.0f - (float)h);
  const float l2g = log2f(gamma);
  const float gC = exp2f(64.0f * l2g);
  if (tid < 64) sCK[tid] = exp2f((float)(63 - tid) * l2g);
  const int i = tid & 63, eg = tid >> 6;   // o-phase: row i, e-pair 2*eg
  const int e0 = eg << 1;
  const float cq = exp2f((float)(i + 1) * l2g);
  const int sr = tid >> 2, sc0 = (tid & 3) << 6;   // q staging role
  const int vr = tid >> 2, vc = (tid & 3) << 1;    // v staging role

  for (int ch = 0; ch < NCH; ch++) {
    const int n0 = ch << 6;
    // ---- stage q chunk and v block ----
    {
      const u16* src = Q + (size_t)(b * NS + n0 + sr) * DM + h * DKH + sc0;
#pragma unroll
      for (int u = 0; u < 8; u++) {
        uint4 v = *(const uint4*)(src + u * 8);
        u32* d = (u32*)&sQ[sr][sc0 + u * 8];
        d[0] = v.x; d[1] = v.y; d[2] = v.z; d[3] = v.w;
      }
      const u16* vsrc = V + (size_t)(b * NS + n0 + vr) * VD + h * DVH + (eb << 3) + vc;
      *(u32*)&sV[vr][vc] = *(const u32*)vsrc;
    }
    __syncthreads();
    // ---- output phase: o = attn@v + cq * (q @ S_prev) ----
    {
      float a0 = 0.f, a1 = 0.f;
      const float* arow = AttnT + ((size_t)((b * 4 + h) * 64 + ch) << 12) + i;
#pragma unroll 4
      for (int j = 0; j < 64; j++) {
        float a = arow[(size_t)j << 6];
        float v0, v1; unpack2(*(const u32*)&sV[j][e0], v0, v1);
        a0 += a * v0; a1 += a * v1;
      }
      if (ch > 0) {
        float s0 = 0.f, s1 = 0.f;
#pragma unroll 4
        for (int d = 0; d < 256; d += 2) {
          float qlo, qhi; unpack2(*(const u32*)&sQ[i][d], qlo, qhi);
          float2 sa = *(const float2*)&sS[d][e0];
          float2 sb = *(const float2*)&sS[d + 1][e0];
          s0 += qlo * sa.x + qhi * sb.x;
          s1 += qlo * sa.y + qhi * sb.y;
        }
        a0 += cq * s0; a1 += cq * s1;
      }
      size_t ob = (size_t)(b * NS + n0 + i) * VD + h * DVH + (eb << 3) + e0;
      u32 packed = (u32)f2bf(a0) | ((u32)f2bf(a1) << 16);
      *(u32*)(O + ob) = packed;
    }
    __syncthreads();
    // ---- state update: S = gC*S + sum_j ck_j k_j v_j^T (thread d = tid) ----
    {
      float sr8[8];
      if (ch == 0) {
#pragma unroll
        for (int e = 0; e < 8; e++) sr8[e] = 0.f;
      } else {
#pragma unroll
        for (int e = 0; e < 8; e++) sr8[e] = gC * sS[tid][e];
      }
      const u16* krow = Kb + (size_t)(b * NS + n0) * DM + h * DKH + tid;
#pragma unroll 2
      for (int j = 0; j < 64; j++) {
        float kd = bf2f(krow[(size_t)j * DM]) * sCK[j];
        uint4 vv = *(const uint4*)&sV[j][0];
        float vf[8]; unpack8(vv, vf);
#pragma unroll
        for (int e = 0; e < 8; e++) sr8[e] += kd * vf[e];
      }
#pragma unroll
      for (int e = 0; e < 8; e++) sS[tid][e] = sr8[e];
    }
    __syncthreads();
  }
}

// ---------------- groupnorm (rms over 512 per head) * silu(gate) ----------------
__global__ __launch_bounds__(256) void norm_gate_kernel(const u16* __restrict__ O,
                                                        const u16* __restrict__ G,
                                                        const float* __restrict__ gnw,
                                                        u16* __restrict__ OG) {
  const int bn = blockIdx.x;            // 0..B*N-1
  const int wave = threadIdx.x >> 6;    // head
  const int lane = threadIdx.x & 63;
  const size_t base = (size_t)bn * VD + (size_t)wave * DVH;
  float vals[8];
  float ss = 0.f;
#pragma unroll
  for (int k = 0; k < 8; k++) {
    float v = bf2f(O[base + lane + 64 * k]);
    vals[k] = v;
    ss += v * v;
  }
#pragma unroll
  for (int off = 32; off > 0; off >>= 1) ss += __shfl_xor(ss, off, 64);
  const float r = rsqrtf(ss * (1.0f / 512.0f) + 1e-5f);
#pragma unroll
  for (int k = 0; k < 8; k++) {
    int e = lane + 64 * k;
    float g = bf2f(G[base + e]);
    float sig = 1.0f / (1.0f + expf(-g));
    OG[base + e] = f2bf(vals[k] * r * gnw[e] * g * sig);
  }
}

// ---------------- launch ----------------
extern "C" void kernel_launch(void* const* d_in, const int* in_sizes, int n_in,
                              void* d_out, int out_size, void* d_ws, size_t ws_size,
                              hipStream_t stream) {
  const float* x   = (const float*)d_in[0];
  const float* Wq  = (const float*)d_in[1];
  const float* Wk  = (const float*)d_in[2];
  const float* Wv  = (const float*)d_in[3];
  const float* Wg  = (const float*)d_in[4];
  const float* Wo  = (const float*)d_in[5];
  const float* gnw = (const float*)d_in[6];

  char* ws = (char*)d_ws;
  u16*   Qb = (u16*)(ws);                          // 16 MB  (8192x1024 bf16)
  u16*   Kb = (u16*)(ws + (16u << 20));            // 16 MB
  u16*   Vb = (u16*)(ws + (32u << 20));            // 32 MB  (8192x2048 bf16)
  u16*   Gb = (u16*)(ws + (64u << 20));            // 32 MB
  float* At = (float*)(ws + (96u << 20));          // 8 MB   (512 x 64 x 64 f32)
  u16*   Ob = (u16*)(ws + (104u << 20));           // 32 MB  (8192x2048 bf16)
  u16*   OG = (u16*)(ws);                          // overlay dead Q+K (32 MB)

  dim3 blk(256);
  const int M = NBAT * NS;   // 8192
  gemm64<false, true><<<dim3(16, 128), blk, 0, stream>>>(x, Wq, Qb, M, DM, DM);
  gemm64<false, true><<<dim3(16, 128), blk, 0, stream>>>(x, Wk, Kb, M, DM, DM);
  gemm64<false, true><<<dim3(32, 128), blk, 0, stream>>>(x, Wv, Vb, M, VD, DM);
  gemm64<false, true><<<dim3(32, 128), blk, 0, stream>>>(x, Wg, Gb, M, VD, DM);
  rope_kernel<<<16384, blk, 0, stream>>>(Qb, Kb);
  attn_kernel<<<512, blk, 0, stream>>>(Qb, Kb, At);
  scan_kernel<<<512, blk, 0, stream>>>(Qb, Kb, Vb, At, Ob);
  norm_gate_kernel<<<M, blk, 0, stream>>>(Ob, Gb, gnw, OG);
  gemm64<true, false><<<dim3(16, 128), blk, 0, stream>>>(OG, Wo, (float*)d_out, M, DM, VD);
}

// Round 2
// 1567.118 us; speedup vs baseline: 1.9557x; 1.9557x over previous
//
#include <hip/hip_runtime.h>

// ---------------- problem constants ----------------
#define NS   4096      // sequence length
#define NBAT 2         // batch
#define NH   4         // heads
#define DKH  256       // head qk dim
#define DVH  512       // head v dim
#define DM   1024      // d_model
#define VD   2048      // value dim
#define CH   64        // chunk
#define NCH  64        // num chunks

typedef unsigned short u16;
typedef unsigned int   u32;

using bf16x8 = __attribute__((ext_vector_type(8))) short;
using f32x4  = __attribute__((ext_vector_type(4))) float;

__device__ __forceinline__ float bf2f(u16 a) {
  return __uint_as_float(((u32)a) << 16);
}
__device__ __forceinline__ u16 f2bf(float f) {
  u32 u = __float_as_uint(f);
  u32 r = (u + 0x7fffu + ((u >> 16) & 1u)) >> 16;   // RNE
  return (u16)r;
}
__device__ __forceinline__ void unpack2(u32 v, float& lo, float& hi) {
  lo = __uint_as_float(v << 16);
  hi = __uint_as_float(v & 0xffff0000u);
}
__device__ __forceinline__ void unpack8(uint4 v, float* f) {
  unpack2(v.x, f[0], f[1]); unpack2(v.y, f[2], f[3]);
  unpack2(v.z, f[4], f[5]); unpack2(v.w, f[6], f[7]);
}

__device__ __forceinline__ void gl_lds16(const u16* g, u16* l) {
  __builtin_amdgcn_global_load_lds(
      (const __attribute__((address_space(1))) void*)g,
      (__attribute__((address_space(3))) void*)l,
      16, 0, 0);
}

// ---------------- f32 -> bf16 convert ----------------
__global__ __launch_bounds__(256) void cvt_bf16(const float* __restrict__ X,
                                                u16* __restrict__ Y) {
  size_t t = (size_t)blockIdx.x * 256 + threadIdx.x;
  float4 v = *(const float4*)(X + t * 4);
  ushort4 o;
  o.x = f2bf(v.x); o.y = f2bf(v.y); o.z = f2bf(v.z); o.w = f2bf(v.w);
  *(ushort4*)(Y + t * 4) = o;
}

// ---------------- f32 KxN -> bf16 NxK transpose-convert ----------------
__global__ __launch_bounds__(256) void transpose_bf16(const float* __restrict__ W,
                                                      u16* __restrict__ Wt,
                                                      int K, int N) {
  __shared__ float tile[64][65];
  const int n0 = blockIdx.x * 64, k0 = blockIdx.y * 64;
  const int t = threadIdx.x;
  const int r = t >> 4, c = (t & 15) << 2;
#pragma unroll
  for (int it = 0; it < 4; it++) {
    float4 v = *(const float4*)(W + (size_t)(k0 + r + it * 16) * N + n0 + c);
    tile[r + it * 16][c + 0] = v.x; tile[r + it * 16][c + 1] = v.y;
    tile[r + it * 16][c + 2] = v.z; tile[r + it * 16][c + 3] = v.w;
  }
  __syncthreads();
#pragma unroll
  for (int it = 0; it < 4; it++) {
    const int nr = r + it * 16;
    ushort4 o;
    o.x = f2bf(tile[c + 0][nr]); o.y = f2bf(tile[c + 1][nr]);
    o.z = f2bf(tile[c + 2][nr]); o.w = f2bf(tile[c + 3][nr]);
    *(ushort4*)(Wt + (size_t)(n0 + nr) * K + k0 + c) = o;
  }
}

// ---------------- MFMA GEMM: C = A @ Bt^T ----------------
// A: MxK bf16 row-major; Bt: NxK bf16 row-major (B transposed); C: MxN.
// 128x128 tile, BK=64, 256 threads (4 waves), each wave 64x64 via 4x4 MFMA tiles.
template<bool OBF>
__global__ __launch_bounds__(256) void gemm_mfma(const u16* __restrict__ A,
                                                 const u16* __restrict__ Bt,
                                                 void* __restrict__ C,
                                                 int M, int N, int K) {
  __shared__ u16 sA[128 * 64];
  __shared__ u16 sB[128 * 64];
  const int tid = threadIdx.x;
  const int wave = tid >> 6, lane = tid & 63;
  const int wm = (wave >> 1) << 6;
  const int wn = (wave & 1) << 6;
  const int row0 = blockIdx.y << 7, col0 = blockIdx.x << 7;

  const int srow = tid >> 3;          // 0..31
  const int sk   = (tid & 7) << 3;    // 0..56

  const u16* aRow = A + (size_t)(row0 + srow) * K + sk;
  const u16* bRow = Bt + (size_t)(col0 + srow) * K + sk;
  u16* sAp = sA + tid * 8;
  u16* sBp = sB + tid * 8;

  f32x4 acc[4][4] = {};

  const int fm = lane & 15;
  const int fk = (lane >> 4) << 3;
  const u16* sAf = sA + (wm + fm) * 64 + fk;
  const u16* sBf = sB + (wn + fm) * 64 + fk;

  for (int k0 = 0; k0 < K; k0 += 64) {
#pragma unroll
    for (int it = 0; it < 4; it++) {
      gl_lds16(aRow + (size_t)(it * 32) * K + k0, sAp + it * 2048);
      gl_lds16(bRow + (size_t)(it * 32) * K + k0, sBp + it * 2048);
    }
    __syncthreads();
#pragma unroll
    for (int kk = 0; kk < 64; kk += 32) {
      bf16x8 af[4], bfr[4];
#pragma unroll
      for (int mt = 0; mt < 4; mt++) af[mt] = *(const bf16x8*)(sAf + mt * 1024 + kk);
#pragma unroll
      for (int nt = 0; nt < 4; nt++) bfr[nt] = *(const bf16x8*)(sBf + nt * 1024 + kk);
#pragma unroll
      for (int mt = 0; mt < 4; mt++)
#pragma unroll
        for (int nt = 0; nt < 4; nt++)
          acc[mt][nt] = __builtin_amdgcn_mfma_f32_16x16x32_bf16(af[mt], bfr[nt], acc[mt][nt], 0, 0, 0);
    }
    __syncthreads();
  }

  const int er = lane >> 4;
  const int ec = lane & 15;
#pragma unroll
  for (int mt = 0; mt < 4; mt++) {
#pragma unroll
    for (int nt = 0; nt < 4; nt++) {
#pragma unroll
      for (int r = 0; r < 4; r++) {
        const size_t row = (size_t)row0 + wm + mt * 16 + er * 4 + r;
        const size_t col = (size_t)col0 + wn + nt * 16 + ec;
        if constexpr (OBF) ((u16*)C)[row * N + col] = f2bf(acc[mt][nt][r]);
        else               ((float*)C)[row * N + col] = acc[mt][nt][r];
      }
    }
  }
}

// ---------------- RoPE (in-place on bf16 Q,K) + q scale ----------------
__global__ __launch_bounds__(256) void rope_kernel(u16* __restrict__ Q, u16* __restrict__ K) {
  size_t t = (size_t)blockIdx.x * 256 + threadIdx.x;   // B*N*NH*128 total
  int j = (int)(t & 127);
  int h = (int)((t >> 7) & 3);
  size_t bn = t >> 9;
  int n = (int)(bn & (NS - 1));
  float ang = (float)n * exp2f(-(float)j * (13.2877123795494f / 128.0f));
  float s, c;
  sincosf(ang, &s, &c);
  size_t base = bn * DM + (size_t)h * DKH + j;
  const float sc = 0.0625f;   // HEAD_QK^-0.5
  float q1 = bf2f(Q[base]), q2 = bf2f(Q[base + 128]);
  Q[base]       = f2bf((q1 * c - q2 * s) * sc);
  Q[base + 128] = f2bf((q2 * c + q1 * s) * sc);
  float k1 = bf2f(K[base]), k2 = bf2f(K[base + 128]);
  K[base]       = f2bf(k1 * c - k2 * s);
  K[base + 128] = f2bf(k2 * c + k1 * s);
}

// ---------------- attention scores with decay, per (b,h,chunk) ----------------
__global__ __launch_bounds__(256) void attn_kernel(const u16* __restrict__ Q,
                                                   const u16* __restrict__ Kb,
                                                   float* __restrict__ AttnT) {
  __shared__ u16 sK[64][264];
  const int wg = blockIdx.x;          // (b*4+h)*64 + tc
  const int tc = wg & 63, h = (wg >> 6) & 3, b = wg >> 8;
  const int n0 = tc << 6;
  const int tid = threadIdx.x;
  {
    const int r = tid >> 2, c0 = (tid & 3) << 6;
    const u16* src = Kb + (size_t)(b * NS + n0 + r) * DM + h * DKH + c0;
#pragma unroll
    for (int u = 0; u < 8; u++)
      *(uint4*)&sK[r][c0 + u * 8] = *(const uint4*)(src + u * 8);
  }
  __syncthreads();
  const int i = tid >> 2, jg = tid & 3;
  const u16* qrow = Q + (size_t)(b * NS + n0 + i) * DM + h * DKH;
  float acc[16] = {};
  for (int d0 = 0; d0 < 256; d0 += 8) {
    uint4 qv = *(const uint4*)(qrow + d0);
    float qf[8]; unpack8(qv, qf);
#pragma unroll
    for (int jj = 0; jj < 16; jj++) {
      uint4 kv = *(const uint4*)&sK[jg * 16 + jj][d0];
      float kf[8]; unpack8(kv, kf);
#pragma unroll
      for (int u = 0; u < 8; u++) acc[jj] += qf[u] * kf[u];
    }
  }
  const float gamma = 1.0f - exp2f(-5.0f - (float)h);
  const float l2g = log2f(gamma);
  float* dst = AttnT + ((size_t)wg << 12) + i;
#pragma unroll
  for (int jj = 0; jj < 16; jj++) {
    int j = jg * 16 + jj;
    int rel = i - j;
    float v = (rel >= 0) ? acc[jj] * exp2f((float)rel * l2g) : 0.0f;
    dst[(size_t)j << 6] = v;
  }
}

// ---------------- retention scan ----------------
// 512 wgs: (b,h,eb). O is written IN-PLACE over V (same buffer): each wg
// stages its V chunk to LDS behind __syncthreads before overwriting those
// exact addresses; (b,h,eb) address sets are disjoint across wgs.
__global__ __launch_bounds__(256) void scan_kernel(const u16* __restrict__ Q,
                                                   const u16* __restrict__ Kb,
                                                   const u16* V,
                                                   const float* __restrict__ AttnT,
                                                   u16* O) {
  __shared__ u16 sQ[64][258];
  __shared__ float sS[256][10];
  __shared__ u16 sV[64][8];
  __shared__ float sCK[64];
  const int wg = blockIdx.x;
  const int eb = wg & 63, h = (wg >> 6) & 3, b = wg >> 8;
  const int tid = threadIdx.x;
  const float gamma = 1.0f - exp2f(-5.0f - (float)h);
  const float l2g = log2f(gamma);
  const float gC = exp2f(64.0f * l2g);
  if (tid < 64) sCK[tid] = exp2f((float)(63 - tid) * l2g);
  const int i = tid & 63, eg = tid >> 6;
  const int e0 = eg << 1;
  const float cq = exp2f((float)(i + 1) * l2g);
  const int sr = tid >> 2, sc0 = (tid & 3) << 6;
  const int vr = tid >> 2, vc = (tid & 3) << 1;

  for (int ch = 0; ch < NCH; ch++) {
    const int n0 = ch << 6;
    {
      const u16* src = Q + (size_t)(b * NS + n0 + sr) * DM + h * DKH + sc0;
#pragma unroll
      for (int u = 0; u < 8; u++) {
        uint4 v = *(const uint4*)(src + u * 8);
        u32* d = (u32*)&sQ[sr][sc0 + u * 8];
        d[0] = v.x; d[1] = v.y; d[2] = v.z; d[3] = v.w;
      }
      const u16* vsrc = V + (size_t)(b * NS + n0 + vr) * VD + h * DVH + (eb << 3) + vc;
      *(u32*)&sV[vr][vc] = *(const u32*)vsrc;
    }
    __syncthreads();
    {
      float a0 = 0.f, a1 = 0.f;
      const float* arow = AttnT + ((size_t)((b * 4 + h) * 64 + ch) << 12) + i;
#pragma unroll 4
      for (int j = 0; j < 64; j++) {
        float a = arow[(size_t)j << 6];
        float v0, v1; unpack2(*(const u32*)&sV[j][e0], v0, v1);
        a0 += a * v0; a1 += a * v1;
      }
      if (ch > 0) {
        float s0 = 0.f, s1 = 0.f;
#pragma unroll 4
        for (int d = 0; d < 256; d += 2) {
          float qlo, qhi; unpack2(*(const u32*)&sQ[i][d], qlo, qhi);
          float2 sa = *(const float2*)&sS[d][e0];
          float2 sb = *(const float2*)&sS[d + 1][e0];
          s0 += qlo * sa.x + qhi * sb.x;
          s1 += qlo * sa.y + qhi * sb.y;
        }
        a0 += cq * s0; a1 += cq * s1;
      }
      size_t ob = (size_t)(b * NS + n0 + i) * VD + h * DVH + (eb << 3) + e0;
      u32 packed = (u32)f2bf(a0) | ((u32)f2bf(a1) << 16);
      *(u32*)(O + ob) = packed;
    }
    __syncthreads();
    {
      float sr8[8];
      if (ch == 0) {
#pragma unroll
        for (int e = 0; e < 8; e++) sr8[e] = 0.f;
      } else {
#pragma unroll
        for (int e = 0; e < 8; e++) sr8[e] = gC * sS[tid][e];
      }
      const u16* krow = Kb + (size_t)(b * NS + n0) * DM + h * DKH + tid;
#pragma unroll 2
      for (int j = 0; j < 64; j++) {
        float kd = bf2f(krow[(size_t)j * DM]) * sCK[j];
        uint4 vv = *(const uint4*)&sV[j][0];
        float vf[8]; unpack8(vv, vf);
#pragma unroll
        for (int e = 0; e < 8; e++) sr8[e] += kd * vf[e];
      }
#pragma unroll
      for (int e = 0; e < 8; e++) sS[tid][e] = sr8[e];
    }
    __syncthreads();
  }
}

// ---------------- groupnorm (rms over 512 per head) * silu(gate) ----------------
__global__ __launch_bounds__(256) void norm_gate_kernel(const u16* __restrict__ O,
                                                        const u16* __restrict__ G,
                                                        const float* __restrict__ gnw,
                                                        u16* __restrict__ OG) {
  const int bn = blockIdx.x;            // 0..B*N-1
  const int wave = threadIdx.x >> 6;    // head
  const int lane = threadIdx.x & 63;
  const size_t base = (size_t)bn * VD + (size_t)wave * DVH;
  float vals[8];
  float ss = 0.f;
#pragma unroll
  for (int k = 0; k < 8; k++) {
    float v = bf2f(O[base + lane + 64 * k]);
    vals[k] = v;
    ss += v * v;
  }
#pragma unroll
  for (int off = 32; off > 0; off >>= 1) ss += __shfl_xor(ss, off, 64);
  const float r = rsqrtf(ss * (1.0f / 512.0f) + 1e-5f);
#pragma unroll
  for (int k = 0; k < 8; k++) {
    int e = lane + 64 * k;
    float g = bf2f(G[base + e]);
    float sig = 1.0f / (1.0f + expf(-g));
    OG[base + e] = f2bf(vals[k] * r * gnw[e] * g * sig);
  }
}

// ---------------- launch ----------------
extern "C" void kernel_launch(void* const* d_in, const int* in_sizes, int n_in,
                              void* d_out, int out_size, void* d_ws, size_t ws_size,
                              hipStream_t stream) {
  const float* x   = (const float*)d_in[0];
  const float* Wq  = (const float*)d_in[1];
  const float* Wk  = (const float*)d_in[2];
  const float* Wv  = (const float*)d_in[3];
  const float* Wg  = (const float*)d_in[4];
  const float* Wo  = (const float*)d_in[5];
  const float* gnw = (const float*)d_in[6];

  char* ws = (char*)d_ws;
  u16*   xb  = (u16*)(ws);                          // 16 MB (dead after projections)
  u16*   Qb  = (u16*)(ws + (16u  << 20));           // 16 MB
  u16*   Kb  = (u16*)(ws + (32u  << 20));           // 16 MB
  u16*   Vb  = (u16*)(ws + (48u  << 20));           // 32 MB (O written in-place)
  u16*   Gb  = (u16*)(ws + (80u  << 20));           // 32 MB
  float* At  = (float*)(ws + (112u << 20));         // 8 MB
  u16*   Wqt = (u16*)(ws + (120u << 20));           // 2 MB
  u16*   Wkt = (u16*)(ws + (122u << 20));           // 2 MB
  u16*   Wvt = (u16*)(ws + (124u << 20));           // 4 MB
  u16*   Wgt = (u16*)(ws + (128u << 20));           // 4 MB
  u16*   Wot = (u16*)(ws + (132u << 20));           // 4 MB  -> total 136 MB
  u16*   OG  = (u16*)(ws);                          // 32 MB overlay (xb+Qb dead)

  dim3 blk(256);
  const int M = NBAT * NS;   // 8192

  cvt_bf16<<<8192, blk, 0, stream>>>(x, xb);                         // 8192*1024 elems
  transpose_bf16<<<dim3(16, 16), blk, 0, stream>>>(Wq, Wqt, DM, DM);
  transpose_bf16<<<dim3(16, 16), blk, 0, stream>>>(Wk, Wkt, DM, DM);
  transpose_bf16<<<dim3(32, 16), blk, 0, stream>>>(Wv, Wvt, DM, VD);
  transpose_bf16<<<dim3(32, 16), blk, 0, stream>>>(Wg, Wgt, DM, VD);
  transpose_bf16<<<dim3(16, 32), blk, 0, stream>>>(Wo, Wot, VD, DM);

  gemm_mfma<true><<<dim3(8, 64),  blk, 0, stream>>>(xb, Wqt, Qb, M, DM, DM);
  gemm_mfma<true><<<dim3(8, 64),  blk, 0, stream>>>(xb, Wkt, Kb, M, DM, DM);
  gemm_mfma<true><<<dim3(16, 64), blk, 0, stream>>>(xb, Wvt, Vb, M, VD, DM);
  gemm_mfma<true><<<dim3(16, 64), blk, 0, stream>>>(xb, Wgt, Gb, M, VD, DM);

  rope_kernel<<<16384, blk, 0, stream>>>(Qb, Kb);
  attn_kernel<<<512, blk, 0, stream>>>(Qb, Kb, At);
  scan_kernel<<<512, blk, 0, stream>>>(Qb, Kb, Vb, At, Vb);
  norm_gate_kernel<<<M, blk, 0, stream>>>(Vb, Gb, gnw, OG);

  gemm_mfma<false><<<dim3(8, 64), blk, 0, stream>>>(OG, Wot, (float*)d_out, M, DM, VD);
}

// Round 3
// 593.946 us; speedup vs baseline: 5.1601x; 2.6385x over previous
//
#include <hip/hip_runtime.h>

// ---------------- problem constants ----------------
#define NS   4096      // sequence length
#define NBAT 2         // batch
#define NH   4         // heads
#define DKH  256       // head qk dim
#define DVH  512       // head v dim
#define DM   1024      // d_model
#define VD   2048      // value dim
#define CH   64        // chunk
#define NCH  64        // num chunks

typedef unsigned short u16;
typedef unsigned int   u32;

using bf16x8 = __attribute__((ext_vector_type(8))) short;
using f32x4  = __attribute__((ext_vector_type(4))) float;

__device__ __forceinline__ float bf2f(u16 a) {
  return __uint_as_float(((u32)a) << 16);
}
__device__ __forceinline__ u16 f2bf(float f) {
  u32 u = __float_as_uint(f);
  u32 r = (u + 0x7fffu + ((u >> 16) & 1u)) >> 16;   // RNE
  return (u16)r;
}
__device__ __forceinline__ void unpack2(u32 v, float& lo, float& hi) {
  lo = __uint_as_float(v << 16);
  hi = __uint_as_float(v & 0xffff0000u);
}
__device__ __forceinline__ void unpack8(uint4 v, float* f) {
  unpack2(v.x, f[0], f[1]); unpack2(v.y, f[2], f[3]);
  unpack2(v.z, f[4], f[5]); unpack2(v.w, f[6], f[7]);
}

__device__ __forceinline__ void gl_lds16(const u16* g, u16* l) {
  __builtin_amdgcn_global_load_lds(
      (const __attribute__((address_space(1))) void*)g,
      (__attribute__((address_space(3))) void*)l,
      16, 0, 0);
}

// ---------------- f32 -> bf16 convert ----------------
__global__ __launch_bounds__(256) void cvt_bf16(const float* __restrict__ X,
                                                u16* __restrict__ Y) {
  size_t t = (size_t)blockIdx.x * 256 + threadIdx.x;
  float4 v = *(const float4*)(X + t * 4);
  ushort4 o;
  o.x = f2bf(v.x); o.y = f2bf(v.y); o.z = f2bf(v.z); o.w = f2bf(v.w);
  *(ushort4*)(Y + t * 4) = o;
}

// ---------------- f32 KxN -> bf16 NxK transpose-convert ----------------
__global__ __launch_bounds__(256) void transpose_bf16(const float* __restrict__ W,
                                                      u16* __restrict__ Wt,
                                                      int K, int N) {
  __shared__ float tile[64][65];
  const int n0 = blockIdx.x * 64, k0 = blockIdx.y * 64;
  const int t = threadIdx.x;
  const int r = t >> 4, c = (t & 15) << 2;
#pragma unroll
  for (int it = 0; it < 4; it++) {
    float4 v = *(const float4*)(W + (size_t)(k0 + r + it * 16) * N + n0 + c);
    tile[r + it * 16][c + 0] = v.x; tile[r + it * 16][c + 1] = v.y;
    tile[r + it * 16][c + 2] = v.z; tile[r + it * 16][c + 3] = v.w;
  }
  __syncthreads();
#pragma unroll
  for (int it = 0; it < 4; it++) {
    const int nr = r + it * 16;
    ushort4 o;
    o.x = f2bf(tile[c + 0][nr]); o.y = f2bf(tile[c + 1][nr]);
    o.z = f2bf(tile[c + 2][nr]); o.w = f2bf(tile[c + 3][nr]);
    *(ushort4*)(Wt + (size_t)(n0 + nr) * K + k0 + c) = o;
  }
}

// ---------------- MFMA GEMM: C = A @ Bt^T ----------------
template<bool OBF>
__global__ __launch_bounds__(256) void gemm_mfma(const u16* __restrict__ A,
                                                 const u16* __restrict__ Bt,
                                                 void* __restrict__ C,
                                                 int M, int N, int K) {
  __shared__ u16 sA[128 * 64];
  __shared__ u16 sB[128 * 64];
  const int tid = threadIdx.x;
  const int wave = tid >> 6, lane = tid & 63;
  const int wm = (wave >> 1) << 6;
  const int wn = (wave & 1) << 6;
  const int row0 = blockIdx.y << 7, col0 = blockIdx.x << 7;

  const int srow = tid >> 3;
  const int sk   = (tid & 7) << 3;

  const u16* aRow = A + (size_t)(row0 + srow) * K + sk;
  const u16* bRow = Bt + (size_t)(col0 + srow) * K + sk;
  u16* sAp = sA + tid * 8;
  u16* sBp = sB + tid * 8;

  f32x4 acc[4][4] = {};

  const int fm = lane & 15;
  const int fk = (lane >> 4) << 3;
  const u16* sAf = sA + (wm + fm) * 64 + fk;
  const u16* sBf = sB + (wn + fm) * 64 + fk;

  for (int k0 = 0; k0 < K; k0 += 64) {
#pragma unroll
    for (int it = 0; it < 4; it++) {
      gl_lds16(aRow + (size_t)(it * 32) * K + k0, sAp + it * 2048);
      gl_lds16(bRow + (size_t)(it * 32) * K + k0, sBp + it * 2048);
    }
    __syncthreads();
#pragma unroll
    for (int kk = 0; kk < 64; kk += 32) {
      bf16x8 af[4], bfr[4];
#pragma unroll
      for (int mt = 0; mt < 4; mt++) af[mt] = *(const bf16x8*)(sAf + mt * 1024 + kk);
#pragma unroll
      for (int nt = 0; nt < 4; nt++) bfr[nt] = *(const bf16x8*)(sBf + nt * 1024 + kk);
#pragma unroll
      for (int mt = 0; mt < 4; mt++)
#pragma unroll
        for (int nt = 0; nt < 4; nt++)
          acc[mt][nt] = __builtin_amdgcn_mfma_f32_16x16x32_bf16(af[mt], bfr[nt], acc[mt][nt], 0, 0, 0);
    }
    __syncthreads();
  }

  const int er = lane >> 4;
  const int ec = lane & 15;
#pragma unroll
  for (int mt = 0; mt < 4; mt++) {
#pragma unroll
    for (int nt = 0; nt < 4; nt++) {
#pragma unroll
      for (int r = 0; r < 4; r++) {
        const size_t row = (size_t)row0 + wm + mt * 16 + er * 4 + r;
        const size_t col = (size_t)col0 + wn + nt * 16 + ec;
        if constexpr (OBF) ((u16*)C)[row * N + col] = f2bf(acc[mt][nt][r]);
        else               ((float*)C)[row * N + col] = acc[mt][nt][r];
      }
    }
  }
}

// ---------------- RoPE (in-place on bf16 Q,K) + q scale ----------------
__global__ __launch_bounds__(256) void rope_kernel(u16* __restrict__ Q, u16* __restrict__ K) {
  size_t t = (size_t)blockIdx.x * 256 + threadIdx.x;   // B*N*NH*128 total
  int j = (int)(t & 127);
  int h = (int)((t >> 7) & 3);
  size_t bn = t >> 9;
  int n = (int)(bn & (NS - 1));
  float ang = (float)n * exp2f(-(float)j * (13.2877123795494f / 128.0f));
  float s, c;
  sincosf(ang, &s, &c);
  size_t base = bn * DM + (size_t)h * DKH + j;
  const float sc = 0.0625f;   // HEAD_QK^-0.5
  float q1 = bf2f(Q[base]), q2 = bf2f(Q[base + 128]);
  Q[base]       = f2bf((q1 * c - q2 * s) * sc);
  Q[base + 128] = f2bf((q2 * c + q1 * s) * sc);
  float k1 = bf2f(K[base]), k2 = bf2f(K[base + 128]);
  K[base]       = f2bf(k1 * c - k2 * s);
  K[base + 128] = f2bf(k2 * c + k1 * s);
}

// ---------------- K -> K^T (per head): KT[b,h,d,n] ----------------
__global__ __launch_bounds__(256) void transpose_k(const u16* __restrict__ Kb,
                                                   u16* __restrict__ KT) {
  __shared__ u16 tile[64][68];
  const int wg = blockIdx.x;
  const int dt = wg & 3, nt = (wg >> 2) & 63, h = (wg >> 8) & 3, b = wg >> 10;
  const int tid = threadIdx.x;
  const int r = tid >> 2, cb = (tid & 3) << 4;
  const u16* src = Kb + (size_t)(b * NS + nt * 64 + r) * DM + h * DKH + dt * 64 + cb;
  *(uint4*)&tile[r][cb]     = *(const uint4*)(src);
  *(uint4*)&tile[r][cb + 8] = *(const uint4*)(src + 8);
  __syncthreads();
  const int dr = tid >> 2, ncb = (tid & 3) << 4;
  u32 w[8];
#pragma unroll
  for (int u = 0; u < 8; u++)
    w[u] = (u32)tile[ncb + 2 * u][dr] | ((u32)tile[ncb + 2 * u + 1][dr] << 16);
  u16* dst = KT + ((size_t)((b * NH + h) * 256) + dt * 64 + dr) * NS + nt * 64 + ncb;
  *(uint4*)(dst)     = make_uint4(w[0], w[1], w[2], w[3]);
  *(uint4*)(dst + 8) = make_uint4(w[4], w[5], w[6], w[7]);
}

// ---------------- attention scores (MFMA) with decay, bf16 out [i][j] ----------------
__global__ __launch_bounds__(256) void attn_mfma(const u16* __restrict__ Q,
                                                 const u16* __restrict__ Kb,
                                                 u16* __restrict__ At) {
  __shared__ u16 sQ[64][264];
  __shared__ u16 sK[64][264];
  const int wg = blockIdx.x;          // (b*4+h)*64 + c
  const int c = wg & 63, h = (wg >> 6) & 3, b = wg >> 8;
  const int n0 = c << 6;
  const int tid = threadIdx.x;
  const int wave = tid >> 6, lane = tid & 63;
  const int quad = lane >> 4, col = lane & 15;
  {
    const int r = tid >> 2, cb = (tid & 3) << 6;
    const u16* qsrc = Q  + (size_t)(b * NS + n0 + r) * DM + h * DKH + cb;
    const u16* ksrc = Kb + (size_t)(b * NS + n0 + r) * DM + h * DKH + cb;
#pragma unroll
    for (int u = 0; u < 8; u++) {
      *(uint4*)&sQ[r][cb + u * 8] = *(const uint4*)(qsrc + u * 8);
      *(uint4*)&sK[r][cb + u * 8] = *(const uint4*)(ksrc + u * 8);
    }
  }
  __syncthreads();
  const int i0 = wave << 4;
  f32x4 acc[4] = {};
#pragma unroll
  for (int ks = 0; ks < 256; ks += 32) {
    bf16x8 a = *(const bf16x8*)&sQ[i0 + col][ks + quad * 8];
#pragma unroll
    for (int nt = 0; nt < 4; nt++) {
      bf16x8 bb = *(const bf16x8*)&sK[nt * 16 + col][ks + quad * 8];
      acc[nt] = __builtin_amdgcn_mfma_f32_16x16x32_bf16(a, bb, acc[nt], 0, 0, 0);
    }
  }
  const float l2g = log2f(1.0f - exp2f(-5.0f - (float)h));
  u16* dst = At + ((size_t)wg << 12);
#pragma unroll
  for (int nt = 0; nt < 4; nt++) {
    int j = nt * 16 + col;
#pragma unroll
    for (int rr = 0; rr < 4; rr++) {
      int i = i0 + quad * 4 + rr;
      int rel = i - j;
      float v = (rel >= 0) ? acc[nt][rr] * exp2f((float)rel * l2g) : 0.0f;
      dst[i * 64 + j] = f2bf(v);
    }
  }
}

// ---------------- fused retention scan (MFMA) ----------------
// 128 wgs: (b,h,es) es = 32-col slice of the 512-wide head value dim.
// Per wave: S slice (64 d x 32 e) persists in f32x4 accumulators; bf16
// write-through copy in sSb for next chunk's o_inter B-operand.
// o written IN-PLACE over V (staged to LDS behind barrier first).
__global__ __launch_bounds__(256) void scan_mfma(const u16* __restrict__ Q,
                                                 const u16* __restrict__ KT,
                                                 const u16* __restrict__ At,
                                                 u16* V) {
  __shared__ u16 sQ[64][264];    // q rows [i][d]        (b128 frags, stride 132dw%32=4)
  __shared__ u16 sKT[256][72];   // K^T [d][j]           (stride 36dw%32=4)
  __shared__ u16 sAi[64][72];    // attn [i][j]
  __shared__ u16 sVT[32][72];    // V^T [e][j]
  __shared__ u16 sVkT[32][72];   // (ck*V)^T [e][j]
  __shared__ u16 sSb[32][264];   // S^T bf16 [e][d]

  const int wg = blockIdx.x;
  const int es = wg & 15, h = (wg >> 4) & 3, b = wg >> 6;
  const int tid = threadIdx.x;
  const int wave = tid >> 6, lane = tid & 63;
  const int quad = lane >> 4, col = lane & 15;

  const float gamma = 1.0f - exp2f(-5.0f - (float)h);
  const float l2g = log2f(gamma);
  const float gC = exp2f(64.0f * l2g);

  // staging roles
  const int qr = tid >> 2, qc = (tid & 3) << 6;      // sQ
  const int ar = tid >> 2, ac = (tid & 3) << 4;      // sAi
  const int vj = tid >> 2, ve = (tid & 3) << 3;      // V
  const float ckj = exp2f((float)(63 - vj) * l2g);

  const int i0 = wave << 4;        // o-phase row base
  const int d0w = wave << 6;       // U-phase d base
  const float cq_base = exp2f((float)(i0 + quad * 4 + 1) * l2g);

  const u16* Qbase  = Q + ((size_t)b * NS) * DM + h * DKH;
  const u16* KTbase = KT + ((size_t)(b * NH + h) * 256) * NS;
  const u16* Atbase = At + ((size_t)((b * NH + h) * NCH) << 12);
  u16* Vbase = V + ((size_t)b * NS) * VD + h * DVH + es * 32;

  f32x4 accU[4][2] = {};

  for (int ch = 0; ch < NCH; ch++) {
    const int n0 = ch << 6;
    // ---- staging ----
    {
      const u16* src = Qbase + (size_t)(n0 + qr) * DM + qc;
#pragma unroll
      for (int u = 0; u < 8; u++)
        *(uint4*)&sQ[qr][qc + u * 8] = *(const uint4*)(src + u * 8);
    }
#pragma unroll
    for (int u = 0; u < 8; u++) {
      int cc = u * 256 + tid;
      int d = cc >> 3, off = (cc & 7) << 3;
      *(uint4*)&sKT[d][off] = *(const uint4*)(KTbase + (size_t)d * NS + n0 + off);
    }
    {
      const u16* src = Atbase + ((size_t)ch << 12) + ar * 64 + ac;
      *(uint4*)&sAi[ar][ac]     = *(const uint4*)(src);
      *(uint4*)&sAi[ar][ac + 8] = *(const uint4*)(src + 8);
    }
    {
      uint4 vv = *(const uint4*)(Vbase + (size_t)(n0 + vj) * VD + ve);
      float vf[8]; unpack8(vv, vf);
      const u16* raw = (const u16*)&vv;
#pragma unroll
      for (int u = 0; u < 8; u++) {
        sVT[ve + u][vj]  = raw[u];
        sVkT[ve + u][vj] = f2bf(vf[u] * ckj);
      }
    }
    __syncthreads();

    // ---- o-phase: o = attn@V + cq*(q@S_prev) ----
    {
      f32x4 ai[2] = {}, ae[2] = {};
#pragma unroll
      for (int ks = 0; ks < 64; ks += 32) {
        bf16x8 a = *(const bf16x8*)&sAi[i0 + col][ks + quad * 8];
#pragma unroll
        for (int nt = 0; nt < 2; nt++) {
          bf16x8 bb = *(const bf16x8*)&sVT[nt * 16 + col][ks + quad * 8];
          ai[nt] = __builtin_amdgcn_mfma_f32_16x16x32_bf16(a, bb, ai[nt], 0, 0, 0);
        }
      }
      if (ch) {
#pragma unroll
        for (int ks = 0; ks < 256; ks += 32) {
          bf16x8 a = *(const bf16x8*)&sQ[i0 + col][ks + quad * 8];
#pragma unroll
          for (int nt = 0; nt < 2; nt++) {
            bf16x8 bb = *(const bf16x8*)&sSb[nt * 16 + col][ks + quad * 8];
            ae[nt] = __builtin_amdgcn_mfma_f32_16x16x32_bf16(a, bb, ae[nt], 0, 0, 0);
          }
        }
      }
      float cq = cq_base;
#pragma unroll
      for (int r = 0; r < 4; r++) {
        int i = i0 + quad * 4 + r;
        u16* dst = Vbase + (size_t)(n0 + i) * VD + col;
#pragma unroll
        for (int nt = 0; nt < 2; nt++)
          dst[nt * 16] = f2bf(ai[nt][r] + cq * ae[nt][r]);
        cq *= gamma;
      }
    }

    // ---- U-phase: S = gC*S + K^T @ (ck*V) ----
#pragma unroll
    for (int mt = 0; mt < 4; mt++)
#pragma unroll
      for (int nt = 0; nt < 2; nt++)
        accU[mt][nt] = accU[mt][nt] * gC;
#pragma unroll
    for (int ks = 0; ks < 64; ks += 32) {
      bf16x8 bb[2];
#pragma unroll
      for (int nt = 0; nt < 2; nt++)
        bb[nt] = *(const bf16x8*)&sVkT[nt * 16 + col][ks + quad * 8];
#pragma unroll
      for (int mt = 0; mt < 4; mt++) {
        bf16x8 a = *(const bf16x8*)&sKT[d0w + mt * 16 + col][ks + quad * 8];
#pragma unroll
        for (int nt = 0; nt < 2; nt++)
          accU[mt][nt] = __builtin_amdgcn_mfma_f32_16x16x32_bf16(a, bb[nt], accU[mt][nt], 0, 0, 0);
      }
    }
    __syncthreads();

    // ---- write-through S -> bf16 (read next chunk) ----
#pragma unroll
    for (int mt = 0; mt < 4; mt++) {
      int d = d0w + mt * 16 + quad * 4;
#pragma unroll
      for (int nt = 0; nt < 2; nt++) {
        int e = nt * 16 + col;
#pragma unroll
        for (int r = 0; r < 4; r++)
          sSb[e][d + r] = f2bf(accU[mt][nt][r]);
      }
    }
  }
}

// ---------------- groupnorm (rms over 512 per head) * silu(gate) ----------------
__global__ __launch_bounds__(256) void norm_gate_kernel(const u16* __restrict__ O,
                                                        const u16* __restrict__ G,
                                                        const float* __restrict__ gnw,
                                                        u16* __restrict__ OG) {
  const int bn = blockIdx.x;            // 0..B*N-1
  const int wave = threadIdx.x >> 6;    // head
  const int lane = threadIdx.x & 63;
  const size_t base = (size_t)bn * VD + (size_t)wave * DVH;
  float vals[8];
  float ss = 0.f;
#pragma unroll
  for (int k = 0; k < 8; k++) {
    float v = bf2f(O[base + lane + 64 * k]);
    vals[k] = v;
    ss += v * v;
  }
#pragma unroll
  for (int off = 32; off > 0; off >>= 1) ss += __shfl_xor(ss, off, 64);
  const float r = rsqrtf(ss * (1.0f / 512.0f) + 1e-5f);
#pragma unroll
  for (int k = 0; k < 8; k++) {
    int e = lane + 64 * k;
    float g = bf2f(G[base + e]);
    float sig = 1.0f / (1.0f + expf(-g));
    OG[base + e] = f2bf(vals[k] * r * gnw[e] * g * sig);
  }
}

// ---------------- launch ----------------
extern "C" void kernel_launch(void* const* d_in, const int* in_sizes, int n_in,
                              void* d_out, int out_size, void* d_ws, size_t ws_size,
                              hipStream_t stream) {
  const float* x   = (const float*)d_in[0];
  const float* Wq  = (const float*)d_in[1];
  const float* Wk  = (const float*)d_in[2];
  const float* Wv  = (const float*)d_in[3];
  const float* Wg  = (const float*)d_in[4];
  const float* Wo  = (const float*)d_in[5];
  const float* gnw = (const float*)d_in[6];

  char* ws = (char*)d_ws;
  u16*   xb  = (u16*)(ws);                          // 16 MB (dead after projections)
  u16*   Qb  = (u16*)(ws + (16u  << 20));           // 16 MB
  u16*   Kb  = (u16*)(ws + (32u  << 20));           // 16 MB
  u16*   Vb  = (u16*)(ws + (48u  << 20));           // 32 MB (O written in-place)
  u16*   Gb  = (u16*)(ws + (80u  << 20));           // 32 MB
  u16*   At  = (u16*)(ws + (112u << 20));           // 4 MB  (512 x 64 x 64 bf16)
  u16*   KTg = (u16*)(ws + (116u << 20));           // 16 MB (b,h,d,n)
  u16*   Wqt = (u16*)(ws + (132u << 20));           // 2 MB
  u16*   Wkt = (u16*)(ws + (134u << 20));           // 2 MB
  u16*   Wvt = (u16*)(ws + (136u << 20));           // 4 MB
  u16*   Wgt = (u16*)(ws + (140u << 20));           // 4 MB
  u16*   Wot = (u16*)(ws + (144u << 20));           // 4 MB  -> total 148 MB
  u16*   OG  = (u16*)(ws);                          // 32 MB overlay (xb+Qb dead)

  dim3 blk(256);
  const int M = NBAT * NS;   // 8192

  cvt_bf16<<<8192, blk, 0, stream>>>(x, xb);
  transpose_bf16<<<dim3(16, 16), blk, 0, stream>>>(Wq, Wqt, DM, DM);
  transpose_bf16<<<dim3(16, 16), blk, 0, stream>>>(Wk, Wkt, DM, DM);
  transpose_bf16<<<dim3(32, 16), blk, 0, stream>>>(Wv, Wvt, DM, VD);
  transpose_bf16<<<dim3(32, 16), blk, 0, stream>>>(Wg, Wgt, DM, VD);
  transpose_bf16<<<dim3(16, 32), blk, 0, stream>>>(Wo, Wot, VD, DM);

  gemm_mfma<true><<<dim3(8, 64),  blk, 0, stream>>>(xb, Wqt, Qb, M, DM, DM);
  gemm_mfma<true><<<dim3(8, 64),  blk, 0, stream>>>(xb, Wkt, Kb, M, DM, DM);
  gemm_mfma<true><<<dim3(16, 64), blk, 0, stream>>>(xb, Wvt, Vb, M, VD, DM);
  gemm_mfma<true><<<dim3(16, 64), blk, 0, stream>>>(xb, Wgt, Gb, M, VD, DM);

  rope_kernel<<<16384, blk, 0, stream>>>(Qb, Kb);
  transpose_k<<<2048, blk, 0, stream>>>(Kb, KTg);
  attn_mfma<<<512, blk, 0, stream>>>(Qb, Kb, At);
  scan_mfma<<<128, blk, 0, stream>>>(Qb, KTg, At, Vb);
  norm_gate_kernel<<<M, blk, 0, stream>>>(Vb, Gb, gnw, OG);

  gemm_mfma<false><<<dim3(8, 64), blk, 0, stream>>>(OG, Wot, (float*)d_out, M, DM, VD);
}

// Round 4
// 550.840 us; speedup vs baseline: 5.5639x; 1.0783x over previous
//
#include <hip/hip_runtime.h>

// ---------------- problem constants ----------------
#define NS   4096      // sequence length
#define NBAT 2         // batch
#define NH   4         // heads
#define DKH  256       // head qk dim
#define DVH  512       // head v dim
#define DM   1024      // d_model
#define VD   2048      // value dim
#define CH   64        // chunk
#define NCH  64        // num chunks

typedef unsigned short u16;
typedef unsigned int   u32;

using bf16x8 = __attribute__((ext_vector_type(8))) short;
using f32x4  = __attribute__((ext_vector_type(4))) float;

__device__ __forceinline__ float bf2f(u16 a) {
  return __uint_as_float(((u32)a) << 16);
}
__device__ __forceinline__ u16 f2bf(float f) {
  u32 u = __float_as_uint(f);
  u32 r = (u + 0x7fffu + ((u >> 16) & 1u)) >> 16;   // RNE
  return (u16)r;
}
__device__ __forceinline__ void unpack2(u32 v, float& lo, float& hi) {
  lo = __uint_as_float(v << 16);
  hi = __uint_as_float(v & 0xffff0000u);
}
__device__ __forceinline__ void unpack8(uint4 v, float* f) {
  unpack2(v.x, f[0], f[1]); unpack2(v.y, f[2], f[3]);
  unpack2(v.z, f[4], f[5]); unpack2(v.w, f[6], f[7]);
}

__device__ __forceinline__ void gl_lds16(const u16* g, u16* l) {
  __builtin_amdgcn_global_load_lds(
      (const __attribute__((address_space(1))) void*)g,
      (__attribute__((address_space(3))) void*)l,
      16, 0, 0);
}

// ---------------- f32 -> bf16 convert ----------------
__global__ __launch_bounds__(256) void cvt_bf16(const float* __restrict__ X,
                                                u16* __restrict__ Y) {
  size_t t = (size_t)blockIdx.x * 256 + threadIdx.x;
  float4 v = *(const float4*)(X + t * 4);
  ushort4 o;
  o.x = f2bf(v.x); o.y = f2bf(v.y); o.z = f2bf(v.z); o.w = f2bf(v.w);
  *(ushort4*)(Y + t * 4) = o;
}

// ---------------- f32 KxN -> bf16 NxK transpose-convert ----------------
__global__ __launch_bounds__(256) void transpose_bf16(const float* __restrict__ W,
                                                      u16* __restrict__ Wt,
                                                      int K, int N) {
  __shared__ float tile[64][65];
  const int n0 = blockIdx.x * 64, k0 = blockIdx.y * 64;
  const int t = threadIdx.x;
  const int r = t >> 4, c = (t & 15) << 2;
#pragma unroll
  for (int it = 0; it < 4; it++) {
    float4 v = *(const float4*)(W + (size_t)(k0 + r + it * 16) * N + n0 + c);
    tile[r + it * 16][c + 0] = v.x; tile[r + it * 16][c + 1] = v.y;
    tile[r + it * 16][c + 2] = v.z; tile[r + it * 16][c + 3] = v.w;
  }
  __syncthreads();
#pragma unroll
  for (int it = 0; it < 4; it++) {
    const int nr = r + it * 16;
    ushort4 o;
    o.x = f2bf(tile[c + 0][nr]); o.y = f2bf(tile[c + 1][nr]);
    o.z = f2bf(tile[c + 2][nr]); o.w = f2bf(tile[c + 3][nr]);
    *(ushort4*)(Wt + (size_t)(n0 + nr) * K + k0 + c) = o;
  }
}

// ---------------- MFMA GEMM: C = A @ Bt^T ----------------
template<bool OBF>
__global__ __launch_bounds__(256) void gemm_mfma(const u16* __restrict__ A,
                                                 const u16* __restrict__ Bt,
                                                 void* __restrict__ C,
                                                 int M, int N, int K) {
  __shared__ u16 sA[128 * 64];
  __shared__ u16 sB[128 * 64];
  const int tid = threadIdx.x;
  const int wave = tid >> 6, lane = tid & 63;
  const int wm = (wave >> 1) << 6;
  const int wn = (wave & 1) << 6;
  const int row0 = blockIdx.y << 7, col0 = blockIdx.x << 7;

  const int srow = tid >> 3;
  const int sk   = (tid & 7) << 3;

  const u16* aRow = A + (size_t)(row0 + srow) * K + sk;
  const u16* bRow = Bt + (size_t)(col0 + srow) * K + sk;
  u16* sAp = sA + tid * 8;
  u16* sBp = sB + tid * 8;

  f32x4 acc[4][4] = {};

  const int fm = lane & 15;
  const int fk = (lane >> 4) << 3;
  const u16* sAf = sA + (wm + fm) * 64 + fk;
  const u16* sBf = sB + (wn + fm) * 64 + fk;

  for (int k0 = 0; k0 < K; k0 += 64) {
#pragma unroll
    for (int it = 0; it < 4; it++) {
      gl_lds16(aRow + (size_t)(it * 32) * K + k0, sAp + it * 2048);
      gl_lds16(bRow + (size_t)(it * 32) * K + k0, sBp + it * 2048);
    }
    __syncthreads();
#pragma unroll
    for (int kk = 0; kk < 64; kk += 32) {
      bf16x8 af[4], bfr[4];
#pragma unroll
      for (int mt = 0; mt < 4; mt++) af[mt] = *(const bf16x8*)(sAf + mt * 1024 + kk);
#pragma unroll
      for (int nt = 0; nt < 4; nt++) bfr[nt] = *(const bf16x8*)(sBf + nt * 1024 + kk);
#pragma unroll
      for (int mt = 0; mt < 4; mt++)
#pragma unroll
        for (int nt = 0; nt < 4; nt++)
          acc[mt][nt] = __builtin_amdgcn_mfma_f32_16x16x32_bf16(af[mt], bfr[nt], acc[mt][nt], 0, 0, 0);
    }
    __syncthreads();
  }

  const int er = lane >> 4;
  const int ec = lane & 15;
#pragma unroll
  for (int mt = 0; mt < 4; mt++) {
#pragma unroll
    for (int nt = 0; nt < 4; nt++) {
#pragma unroll
      for (int r = 0; r < 4; r++) {
        const size_t row = (size_t)row0 + wm + mt * 16 + er * 4 + r;
        const size_t col = (size_t)col0 + wn + nt * 16 + ec;
        if constexpr (OBF) ((u16*)C)[row * N + col] = f2bf(acc[mt][nt][r]);
        else               ((float*)C)[row * N + col] = acc[mt][nt][r];
      }
    }
  }
}

// ---------------- RoPE (in-place on bf16 Q,K) + q scale ----------------
__global__ __launch_bounds__(256) void rope_kernel(u16* __restrict__ Q, u16* __restrict__ K) {
  size_t t = (size_t)blockIdx.x * 256 + threadIdx.x;   // B*N*NH*128 total
  int j = (int)(t & 127);
  int h = (int)((t >> 7) & 3);
  size_t bn = t >> 9;
  int n = (int)(bn & (NS - 1));
  float ang = (float)n * exp2f(-(float)j * (13.2877123795494f / 128.0f));
  float s, c;
  sincosf(ang, &s, &c);
  size_t base = bn * DM + (size_t)h * DKH + j;
  const float sc = 0.0625f;   // HEAD_QK^-0.5
  float q1 = bf2f(Q[base]), q2 = bf2f(Q[base + 128]);
  Q[base]       = f2bf((q1 * c - q2 * s) * sc);
  Q[base + 128] = f2bf((q2 * c + q1 * s) * sc);
  float k1 = bf2f(K[base]), k2 = bf2f(K[base + 128]);
  K[base]       = f2bf(k1 * c - k2 * s);
  K[base + 128] = f2bf(k2 * c + k1 * s);
}

// ---------------- K -> K^T (per head): KT[b,h,d,n] ----------------
__global__ __launch_bounds__(256) void transpose_k(const u16* __restrict__ Kb,
                                                   u16* __restrict__ KT) {
  __shared__ u16 tile[64][68];
  const int wg = blockIdx.x;
  const int dt = wg & 3, nt = (wg >> 2) & 63, h = (wg >> 8) & 3, b = wg >> 10;
  const int tid = threadIdx.x;
  const int r = tid >> 2, cb = (tid & 3) << 4;
  const u16* src = Kb + (size_t)(b * NS + nt * 64 + r) * DM + h * DKH + dt * 64 + cb;
  *(uint4*)&tile[r][cb]     = *(const uint4*)(src);
  *(uint4*)&tile[r][cb + 8] = *(const uint4*)(src + 8);
  __syncthreads();
  const int dr = tid >> 2, ncb = (tid & 3) << 4;
  u32 w[8];
#pragma unroll
  for (int u = 0; u < 8; u++)
    w[u] = (u32)tile[ncb + 2 * u][dr] | ((u32)tile[ncb + 2 * u + 1][dr] << 16);
  u16* dst = KT + ((size_t)((b * NH + h) * 256) + dt * 64 + dr) * NS + nt * 64 + ncb;
  *(uint4*)(dst)     = make_uint4(w[0], w[1], w[2], w[3]);
  *(uint4*)(dst + 8) = make_uint4(w[4], w[5], w[6], w[7]);
}

// ---------------- attention scores (MFMA) with decay, bf16 out [i][j] ----------------
__global__ __launch_bounds__(256) void attn_mfma(const u16* __restrict__ Q,
                                                 const u16* __restrict__ Kb,
                                                 u16* __restrict__ At) {
  __shared__ u16 sQ[64][264];
  __shared__ u16 sK[64][264];
  const int wg = blockIdx.x;          // (b*4+h)*64 + c
  const int c = wg & 63, h = (wg >> 6) & 3, b = wg >> 8;
  const int n0 = c << 6;
  const int tid = threadIdx.x;
  const int wave = tid >> 6, lane = tid & 63;
  const int quad = lane >> 4, col = lane & 15;
  {
    const int r = tid >> 2, cb = (tid & 3) << 6;
    const u16* qsrc = Q  + (size_t)(b * NS + n0 + r) * DM + h * DKH + cb;
    const u16* ksrc = Kb + (size_t)(b * NS + n0 + r) * DM + h * DKH + cb;
#pragma unroll
    for (int u = 0; u < 8; u++) {
      *(uint4*)&sQ[r][cb + u * 8] = *(const uint4*)(qsrc + u * 8);
      *(uint4*)&sK[r][cb + u * 8] = *(const uint4*)(ksrc + u * 8);
    }
  }
  __syncthreads();
  const int i0 = wave << 4;
  f32x4 acc[4] = {};
#pragma unroll
  for (int ks = 0; ks < 256; ks += 32) {
    bf16x8 a = *(const bf16x8*)&sQ[i0 + col][ks + quad * 8];
#pragma unroll
    for (int nt = 0; nt < 4; nt++) {
      bf16x8 bb = *(const bf16x8*)&sK[nt * 16 + col][ks + quad * 8];
      acc[nt] = __builtin_amdgcn_mfma_f32_16x16x32_bf16(a, bb, acc[nt], 0, 0, 0);
    }
  }
  const float l2g = log2f(1.0f - exp2f(-5.0f - (float)h));
  u16* dst = At + ((size_t)wg << 12);
#pragma unroll
  for (int nt = 0; nt < 4; nt++) {
    int j = nt * 16 + col;
#pragma unroll
    for (int rr = 0; rr < 4; rr++) {
      int i = i0 + quad * 4 + rr;
      int rel = i - j;
      float v = (rel >= 0) ? acc[nt][rr] * exp2f((float)rel * l2g) : 0.0f;
      dst[i * 64 + j] = f2bf(v);
    }
  }
}

// ---------------- fused retention scan (MFMA, wave-specialized) ----------------
// 256 wgs: (b,h,es) es = 16-col slice of the 512-wide head value dim.
// 512 threads: waves 0-3 compute o rows (attn@V + cq*q@S_prev);
// waves 4-7 own the S recurrence (64-d slice each) in f32 accumulators with a
// bf16 LDS write-through (sSb) for the next chunk's o_inter B-operand.
// A-operand fragments (Q / K^T / attn rows) are read DIRECTLY from global —
// each frag load is 16 rows x 64B, fully-utilized cache lines, L2/L3-hot.
// Global loads are register double-buffered (prefetch ch+1 during ch compute).
// o is written in-place over V (this wg's V chunk is in LDS before overwrite;
// (b,h,es) column sets are disjoint across wgs, so no cross-wg hazard).
__global__ __launch_bounds__(512, 2) void scan_mfma(const u16* __restrict__ Q,
                                                    const u16* __restrict__ KT,
                                                    const u16* __restrict__ At,
                                                    u16* V) {
  __shared__ u16 sVT[16][72];    // V^T [e][j]
  __shared__ u16 sVkT[16][72];   // (ck*V)^T [e][j]
  __shared__ u16 sSb[16][264];   // S^T bf16 [e][d]

  const int wg = blockIdx.x;
  const int es = wg & 31, h = (wg >> 5) & 3, b = wg >> 7;
  const int tid = threadIdx.x;
  const int wave = tid >> 6, lane = tid & 63;
  const int quad = lane >> 4, col = lane & 15;

  const float gamma = 1.0f - exp2f(-5.0f - (float)h);
  const float l2g = log2f(gamma);
  const float gC = exp2f(64.0f * l2g);

  const bool isO = wave < 4;
  const int i0  = (wave & 3) << 4;   // o-wave: row base
  const int d0w = (wave & 3) << 6;   // U-wave: d base
  const float cq0 = exp2f((float)(i0 + quad * 4 + 1) * l2g);

  const u16* Qb2 = Q  + (size_t)b * NS * DM + h * DKH;          // [n][d]
  const u16* KTb = KT + (size_t)((b * NH + h) * 256) * NS;      // [d][n]
  const u16* Atb = At + ((size_t)((b * NH + h) * NCH) << 12);   // [ch][i][j]
  u16* Vb2 = V + (size_t)b * NS * VD + h * DVH + es * 16;       // [n][e]

  const int vj = (tid & 127) >> 1, ve = (tid & 1) << 3;         // V-stage role
  const float ckj = exp2f((float)(63 - vj) * l2g);

  bf16x8 qf[2][8], af[2][2], kf[2][8];
  uint4 vv[2];

  // ---- prefetch chunk 0 ----
  if (tid < 128) vv[0] = *(const uint4*)(Vb2 + (size_t)vj * VD + ve);
  if (isO) {
    const u16* qrow = Qb2 + (size_t)(i0 + col) * DM + quad * 8;
#pragma unroll
    for (int k = 0; k < 8; k++) qf[0][k] = *(const bf16x8*)(qrow + k * 32);
    const u16* arow = Atb + (i0 + col) * 64 + quad * 8;
    af[0][0] = *(const bf16x8*)(arow);
    af[0][1] = *(const bf16x8*)(arow + 32);
  } else {
#pragma unroll
    for (int mt = 0; mt < 4; mt++) {
      const u16* krow = KTb + (size_t)(d0w + mt * 16 + col) * NS + quad * 8;
      kf[0][mt * 2]     = *(const bf16x8*)(krow);
      kf[0][mt * 2 + 1] = *(const bf16x8*)(krow + 32);
    }
  }

  f32x4 accU[4] = {};

#pragma unroll 2
  for (int ch = 0; ch < NCH; ch++) {
    const int cur = ch & 1, nxt = cur ^ 1;
    const int n0 = ch << 6;
    // ---- V transpose-stage from prefetched regs ----
    if (tid < 128) {
      float vf[8]; unpack8(vv[cur], vf);
      const u16* raw = (const u16*)&vv[cur];
#pragma unroll
      for (int u = 0; u < 8; u++) {
        sVT[ve + u][vj]  = raw[u];
        sVkT[ve + u][vj] = f2bf(vf[u] * ckj);
      }
    }
    __syncthreads();
    // ---- prefetch chunk ch+1 (overlaps with MFMA below) ----
    if (ch + 1 < NCH) {
      const int n1 = n0 + 64;
      if (tid < 128) vv[nxt] = *(const uint4*)(Vb2 + (size_t)(n1 + vj) * VD + ve);
      if (isO) {
        const u16* qrow = Qb2 + (size_t)(n1 + i0 + col) * DM + quad * 8;
#pragma unroll
        for (int k = 0; k < 8; k++) qf[nxt][k] = *(const bf16x8*)(qrow + k * 32);
        const u16* arow = Atb + ((size_t)(ch + 1) << 12) + (i0 + col) * 64 + quad * 8;
        af[nxt][0] = *(const bf16x8*)(arow);
        af[nxt][1] = *(const bf16x8*)(arow + 32);
      } else {
#pragma unroll
        for (int mt = 0; mt < 4; mt++) {
          const u16* krow = KTb + (size_t)(d0w + mt * 16 + col) * NS + n1 + quad * 8;
          kf[nxt][mt * 2]     = *(const bf16x8*)(krow);
          kf[nxt][mt * 2 + 1] = *(const bf16x8*)(krow + 32);
        }
      }
    }
    // ---- compute ----
    if (isO) {
      f32x4 ai = {}, ae = {};
#pragma unroll
      for (int k = 0; k < 2; k++) {
        bf16x8 bb = *(const bf16x8*)&sVT[col][k * 32 + quad * 8];
        ai = __builtin_amdgcn_mfma_f32_16x16x32_bf16(af[cur][k], bb, ai, 0, 0, 0);
      }
      if (ch) {
#pragma unroll
        for (int k = 0; k < 8; k++) {
          bf16x8 bb = *(const bf16x8*)&sSb[col][k * 32 + quad * 8];
          ae = __builtin_amdgcn_mfma_f32_16x16x32_bf16(qf[cur][k], bb, ae, 0, 0, 0);
        }
      }
      float cq = cq0;
#pragma unroll
      for (int r = 0; r < 4; r++) {
        u16* dst = Vb2 + (size_t)(n0 + i0 + quad * 4 + r) * VD + col;
        *dst = f2bf(ai[r] + cq * ae[r]);
        cq *= gamma;
      }
    } else {
#pragma unroll
      for (int mt = 0; mt < 4; mt++) accU[mt] *= gC;
#pragma unroll
      for (int k = 0; k < 2; k++) {
        bf16x8 bb = *(const bf16x8*)&sVkT[col][k * 32 + quad * 8];
#pragma unroll
        for (int mt = 0; mt < 4; mt++)
          accU[mt] = __builtin_amdgcn_mfma_f32_16x16x32_bf16(kf[cur][mt * 2 + k], bb, accU[mt], 0, 0, 0);
      }
    }
    __syncthreads();
    // ---- S write-through (read by o-waves next chunk) ----
    if (!isO) {
#pragma unroll
      for (int mt = 0; mt < 4; mt++) {
        int d = d0w + mt * 16 + quad * 4;
#pragma unroll
        for (int r = 0; r < 4; r++)
          sSb[col][d + r] = f2bf(accU[mt][r]);
      }
    }
  }
}

// ---------------- groupnorm (rms over 512 per head) * silu(gate) ----------------
__global__ __launch_bounds__(256) void norm_gate_kernel(const u16* __restrict__ O,
                                                        const u16* __restrict__ G,
                                                        const float* __restrict__ gnw,
                                                        u16* __restrict__ OG) {
  const int bn = blockIdx.x;            // 0..B*N-1
  const int wave = threadIdx.x >> 6;    // head
  const int lane = threadIdx.x & 63;
  const size_t base = (size_t)bn * VD + (size_t)wave * DVH;
  float vals[8];
  float ss = 0.f;
#pragma unroll
  for (int k = 0; k < 8; k++) {
    float v = bf2f(O[base + lane + 64 * k]);
    vals[k] = v;
    ss += v * v;
  }
#pragma unroll
  for (int off = 32; off > 0; off >>= 1) ss += __shfl_xor(ss, off, 64);
  const float r = rsqrtf(ss * (1.0f / 512.0f) + 1e-5f);
#pragma unroll
  for (int k = 0; k < 8; k++) {
    int e = lane + 64 * k;
    float g = bf2f(G[base + e]);
    float sig = 1.0f / (1.0f + expf(-g));
    OG[base + e] = f2bf(vals[k] * r * gnw[e] * g * sig);
  }
}

// ---------------- launch ----------------
extern "C" void kernel_launch(void* const* d_in, const int* in_sizes, int n_in,
                              void* d_out, int out_size, void* d_ws, size_t ws_size,
                              hipStream_t stream) {
  const float* x   = (const float*)d_in[0];
  const float* Wq  = (const float*)d_in[1];
  const float* Wk  = (const float*)d_in[2];
  const float* Wv  = (const float*)d_in[3];
  const float* Wg  = (const float*)d_in[4];
  const float* Wo  = (const float*)d_in[5];
  const float* gnw = (const float*)d_in[6];

  char* ws = (char*)d_ws;
  u16*   xb  = (u16*)(ws);                          // 16 MB (dead after projections)
  u16*   Qb  = (u16*)(ws + (16u  << 20));           // 16 MB
  u16*   Kb  = (u16*)(ws + (32u  << 20));           // 16 MB
  u16*   Vb  = (u16*)(ws + (48u  << 20));           // 32 MB (O written in-place)
  u16*   Gb  = (u16*)(ws + (80u  << 20));           // 32 MB
  u16*   At  = (u16*)(ws + (112u << 20));           // 4 MB  (512 x 64 x 64 bf16)
  u16*   KTg = (u16*)(ws + (116u << 20));           // 16 MB (b,h,d,n)
  u16*   Wqt = (u16*)(ws + (132u << 20));           // 2 MB
  u16*   Wkt = (u16*)(ws + (134u << 20));           // 2 MB
  u16*   Wvt = (u16*)(ws + (136u << 20));           // 4 MB
  u16*   Wgt = (u16*)(ws + (140u << 20));           // 4 MB
  u16*   Wot = (u16*)(ws + (144u << 20));           // 4 MB  -> total 148 MB
  u16*   OG  = (u16*)(ws);                          // 32 MB overlay (xb+Qb dead)

  dim3 blk(256);
  const int M = NBAT * NS;   // 8192

  cvt_bf16<<<8192, blk, 0, stream>>>(x, xb);
  transpose_bf16<<<dim3(16, 16), blk, 0, stream>>>(Wq, Wqt, DM, DM);
  transpose_bf16<<<dim3(16, 16), blk, 0, stream>>>(Wk, Wkt, DM, DM);
  transpose_bf16<<<dim3(32, 16), blk, 0, stream>>>(Wv, Wvt, DM, VD);
  transpose_bf16<<<dim3(32, 16), blk, 0, stream>>>(Wg, Wgt, DM, VD);
  transpose_bf16<<<dim3(16, 32), blk, 0, stream>>>(Wo, Wot, VD, DM);

  gemm_mfma<true><<<dim3(8, 64),  blk, 0, stream>>>(xb, Wqt, Qb, M, DM, DM);
  gemm_mfma<true><<<dim3(8, 64),  blk, 0, stream>>>(xb, Wkt, Kb, M, DM, DM);
  gemm_mfma<true><<<dim3(16, 64), blk, 0, stream>>>(xb, Wvt, Vb, M, VD, DM);
  gemm_mfma<true><<<dim3(16, 64), blk, 0, stream>>>(xb, Wgt, Gb, M, VD, DM);

  rope_kernel<<<16384, blk, 0, stream>>>(Qb, Kb);
  transpose_k<<<2048, blk, 0, stream>>>(Kb, KTg);
  attn_mfma<<<512, blk, 0, stream>>>(Qb, Kb, At);
  scan_mfma<<<256, dim3(512), 0, stream>>>(Qb, KTg, At, Vb);
  norm_gate_kernel<<<M, blk, 0, stream>>>(Vb, Gb, gnw, OG);

  gemm_mfma<false><<<dim3(8, 64), blk, 0, stream>>>(OG, Wot, (float*)d_out, M, DM, VD);
}